// Round 1
// baseline (1305.487 us; speedup 1.0000x reference)
//
#include <hip/hip_runtime.h>

// Problem constants (fixed by the reference).
#define N_USER 100000
#define N_ITEM 100000
#define NEDGE  500000
#define EMB    128
#define HID    128
#define OUT    64

// ---------------------------------------------------------------------------
// Degree count: one thread per edge, atomicAdd on float count.
// ---------------------------------------------------------------------------
__global__ __launch_bounds__(256) void count_deg_k(
    const int* __restrict__ dst, float* __restrict__ cnt, int E) {
  int t = blockIdx.x * 256 + threadIdx.x;
  if (t < E) atomicAdd(&cnt[dst[t]], 1.0f);
}

// ---------------------------------------------------------------------------
// Edge aggregation: per (edge, dim) thread; gather from src row, atomicAdd
// into dst row. D = feature dim (128 or 64).
// ---------------------------------------------------------------------------
template <int D>
__global__ __launch_bounds__(256) void agg_k(
    const float* __restrict__ msg, const int* __restrict__ src,
    const int* __restrict__ dst, float* __restrict__ acc, int E) {
  constexpr int EPB = 256 / D;  // edges per block
  int e = blockIdx.x * EPB + threadIdx.x / D;
  int d = threadIdx.x % D;
  if (e < E) {
    int s  = src[e];
    int dd = dst[e];
    float v = msg[(size_t)s * D + d];
    atomicAdd(&acc[(size_t)dd * D + d], v);
  }
}

// ---------------------------------------------------------------------------
// GEMM: out = A[M,128] @ W[128,N] + b, optionally fused finalize:
//   out += acc/max(cnt,1), optionally leaky-relu(0.01).
// BM=32 rows/block, 256 threads. W fully staged in LDS, A tile in LDS.
// Thread map: c = tid % N, row-quarter rq = tid / N; each thread computes
// rows rq + i*RPI (i < 32/RPI) at column c.  A-reads are wave-uniform
// (broadcast); W-reads are stride-1 across lanes (conflict-free).
// ---------------------------------------------------------------------------
template <int N, bool FIN, bool LRELU>
__global__ __launch_bounds__(256) void gemm_k(
    const float* __restrict__ A, const float* __restrict__ W,
    const float* __restrict__ b, const float* __restrict__ acc,
    const float* __restrict__ cnt, float* __restrict__ out, int M) {
  constexpr int K = 128;
  constexpr int BM = 32;
  constexpr int RPI = 256 / N;  // 2 (N=128) or 4 (N=64)
  constexpr int NR = BM / RPI;  // 16 or 8 rows per thread

  __shared__ float Ws[K][N];
  __shared__ float As[BM][K];

  int tid = threadIdx.x;
  int row0 = blockIdx.x * BM;

  {  // stage W (K*N floats) via float4
    const float4* Wv = (const float4*)W;
    float4* Wsv = (float4*)&Ws[0][0];
    constexpr int NV = K * N / 4;
#pragma unroll
    for (int i = 0; i < NV / 256; ++i) Wsv[tid + i * 256] = Wv[tid + i * 256];
  }
  {  // stage A tile (BM*K floats) via float4
    const float4* Av = (const float4*)(A + (size_t)row0 * K);
    float4* Asv = (float4*)&As[0][0];
    constexpr int NV = BM * K / 4;  // 1024
#pragma unroll
    for (int i = 0; i < NV / 256; ++i) Asv[tid + i * 256] = Av[tid + i * 256];
  }
  __syncthreads();

  int c = tid % N;
  int rq = tid / N;

  float accu[NR];
#pragma unroll
  for (int i = 0; i < NR; ++i) accu[i] = 0.f;

  for (int k = 0; k < K; k += 4) {
    float w0 = Ws[k + 0][c];
    float w1 = Ws[k + 1][c];
    float w2 = Ws[k + 2][c];
    float w3 = Ws[k + 3][c];
#pragma unroll
    for (int i = 0; i < NR; ++i) {
      float4 a = *(const float4*)&As[rq + i * RPI][k];
      accu[i] += a.x * w0 + a.y * w1 + a.z * w2 + a.w * w3;
    }
  }

  float bias = b[c];
#pragma unroll
  for (int i = 0; i < NR; ++i) {
    int r = row0 + rq + i * RPI;
    float v = accu[i] + bias;
    if (FIN) {
      float cn = cnt[r];
      v += acc[(size_t)r * N + c] / fmaxf(cn, 1.0f);
    }
    if (LRELU) v = (v >= 0.f) ? v : 0.01f * v;
    out[(size_t)r * N + c] = v;
  }
}

extern "C" void kernel_launch(void* const* d_in, const int* in_sizes, int n_in,
                              void* d_out, int out_size, void* d_ws,
                              size_t ws_size, hipStream_t stream) {
  const float* emb_u = (const float*)d_in[0];
  const float* emb_i = (const float*)d_in[1];
  const float* W1_0  = (const float*)d_in[2];
  const float* b1_0  = (const float*)d_in[3];
  const float* W1_ui = (const float*)d_in[4];
  const float* b1_ui = (const float*)d_in[5];
  const float* W1_iu = (const float*)d_in[6];
  const float* b1_iu = (const float*)d_in[7];
  const float* W2_0  = (const float*)d_in[8];
  const float* b2_0  = (const float*)d_in[9];
  const float* W2_ui = (const float*)d_in[10];
  const float* b2_ui = (const float*)d_in[11];
  const float* W2_iu = (const float*)d_in[12];
  const float* b2_iu = (const float*)d_in[13];
  const int* src_ui = (const int*)d_in[14];
  const int* dst_ui = (const int*)d_in[15];
  const int* src_iu = (const int*)d_in[16];
  const int* dst_iu = (const int*)d_in[17];
  float* out = (float*)d_out;

  // Workspace layout (floats): three 100000x128 buffers + two count arrays.
  const size_t NB = (size_t)N_USER * 128;  // 12.8M floats
  float* B0 = (float*)d_ws;                // wh buffers (both layers)
  float* B1 = B0 + NB;                     // acc_i -> h_i
  float* B2 = B1 + NB;                     // acc_u -> h_u
  float* cnt_i = B2 + NB;
  float* cnt_u = cnt_i + N_ITEM;
  float* B0a = B0;                          // layer-2 wh  (100000x64)
  float* B0b = B0 + (size_t)N_USER * 64;    // layer-2 acc (100000x64)

  const int GM = N_USER / 32;  // 3125 blocks per GEMM
  const int EB = (NEDGE + 255) / 256;

  // Degrees (same for both layers).
  hipMemsetAsync(cnt_i, 0, N_ITEM * sizeof(float), stream);
  hipMemsetAsync(cnt_u, 0, N_USER * sizeof(float), stream);
  count_deg_k<<<EB, 256, 0, stream>>>(dst_ui, cnt_i, NEDGE);
  count_deg_k<<<EB, 256, 0, stream>>>(dst_iu, cnt_u, NEDGE);

  // ---------------- Layer 1 (128 -> 128, leaky-relu) ----------------
  // wh_u = emb_u @ W1_ui + b1_ui
  gemm_k<128, false, false><<<GM, 256, 0, stream>>>(
      emb_u, W1_ui, b1_ui, nullptr, nullptr, B0, N_USER);
  // acc_i = segment_sum(wh_u over ui edges)
  hipMemsetAsync(B1, 0, NB * sizeof(float), stream);
  agg_k<128><<<(NEDGE + 1) / 2, 256, 0, stream>>>(B0, src_ui, dst_ui, B1, NEDGE);
  // wh_i = emb_i @ W1_iu + b1_iu   (B0 reusable after agg)
  gemm_k<128, false, false><<<GM, 256, 0, stream>>>(
      emb_i, W1_iu, b1_iu, nullptr, nullptr, B0, N_ITEM);
  // acc_u = segment_sum(wh_i over iu edges)
  hipMemsetAsync(B2, 0, NB * sizeof(float), stream);
  agg_k<128><<<(NEDGE + 1) / 2, 256, 0, stream>>>(B0, src_iu, dst_iu, B2, NEDGE);
  // h_i = lrelu(acc_i/cnt + emb_i @ W1_0 + b1_0)  (in place into B1)
  gemm_k<128, true, true><<<GM, 256, 0, stream>>>(
      emb_i, W1_0, b1_0, B1, cnt_i, B1, N_ITEM);
  // h_u = lrelu(acc_u/cnt + emb_u @ W1_0 + b1_0)  (in place into B2)
  gemm_k<128, true, true><<<GM, 256, 0, stream>>>(
      emb_u, W1_0, b1_0, B2, cnt_u, B2, N_USER);

  // ---------------- Layer 2 (128 -> 64, no activation) ----------------
  // wh_u2 = h_u @ W2_ui + b2_ui
  gemm_k<64, false, false><<<GM, 256, 0, stream>>>(
      B2, W2_ui, b2_ui, nullptr, nullptr, B0a, N_USER);
  hipMemsetAsync(B0b, 0, (size_t)N_ITEM * 64 * sizeof(float), stream);
  agg_k<64><<<(NEDGE + 3) / 4, 256, 0, stream>>>(B0a, src_ui, dst_ui, B0b, NEDGE);
  // out_i = acc/cnt + h_i @ W2_0 + b2_0   -> d_out second half
  gemm_k<64, true, false><<<GM, 256, 0, stream>>>(
      B1, W2_0, b2_0, B0b, cnt_i, out + (size_t)N_USER * 64, N_ITEM);
  // wh_i2 = h_i @ W2_iu + b2_iu
  gemm_k<64, false, false><<<GM, 256, 0, stream>>>(
      B1, W2_iu, b2_iu, nullptr, nullptr, B0a, N_ITEM);
  hipMemsetAsync(B0b, 0, (size_t)N_USER * 64 * sizeof(float), stream);
  agg_k<64><<<(NEDGE + 3) / 4, 256, 0, stream>>>(B0a, src_iu, dst_iu, B0b, NEDGE);
  // out_u = acc/cnt + h_u @ W2_0 + b2_0   -> d_out first half
  gemm_k<64, true, false><<<GM, 256, 0, stream>>>(
      B2, W2_0, b2_0, B0b, cnt_u, out, N_USER);
}

// Round 2
// 459.077 us; speedup vs baseline: 2.8437x; 2.8437x over previous
//
#include <hip/hip_runtime.h>

#define N_USER 100000
#define N_ITEM 100000
#define NEDGE  500000

typedef __attribute__((ext_vector_type(8))) short short8;
typedef __attribute__((ext_vector_type(4))) float f32x4;

__device__ __forceinline__ unsigned short f2bf(float f) {
  union { float f; unsigned int u; } x{f};
  unsigned int r = x.u + 0x7fffu + ((x.u >> 16) & 1u);  // RTN-even
  return (unsigned short)(r >> 16);
}
__device__ __forceinline__ float bf2f(unsigned short u) {
  union { unsigned int u; float f; } x{(unsigned int)u << 16};
  return x.f;
}

// ---------------------------------------------------------------------------
// Weight prep: 4 fused transposed bf16 weight buffers, [N][256] with
// k<128 from W0 and k>=128 from We.  Total 98304 elems -> 384 blocks.
// ---------------------------------------------------------------------------
__global__ __launch_bounds__(256) void prep_wt_k(
    const float* __restrict__ W10, const float* __restrict__ W1ui,
    const float* __restrict__ W1iu, const float* __restrict__ W20,
    const float* __restrict__ W2ui, const float* __restrict__ W2iu,
    unsigned short* __restrict__ WT1i, unsigned short* __restrict__ WT1u,
    unsigned short* __restrict__ WT2i, unsigned short* __restrict__ WT2u) {
  int t = blockIdx.x * 256 + threadIdx.x;
  if (t < 32768) {
    int n = t >> 8, k = t & 255;
    float v = (k < 128) ? W10[k * 128 + n] : W1ui[(k - 128) * 128 + n];
    WT1i[t] = f2bf(v);
  } else if (t < 65536) {
    int q = t - 32768; int n = q >> 8, k = q & 255;
    float v = (k < 128) ? W10[k * 128 + n] : W1iu[(k - 128) * 128 + n];
    WT1u[q] = f2bf(v);
  } else if (t < 81920) {
    int q = t - 65536; int n = q >> 8, k = q & 255;
    float v = (k < 128) ? W20[k * 64 + n] : W2ui[(k - 128) * 64 + n];
    WT2i[q] = f2bf(v);
  } else if (t < 98304) {
    int q = t - 81920; int n = q >> 8, k = q & 255;
    float v = (k < 128) ? W20[k * 64 + n] : W2iu[(k - 128) * 64 + n];
    WT2u[q] = f2bf(v);
  }
}

// ---------------------------------------------------------------------------
// CSR build: count -> scan(3 kernels) -> fill
// ---------------------------------------------------------------------------
__global__ __launch_bounds__(256) void count_k(
    const int* __restrict__ dst, int* __restrict__ cnt, int E) {
  int e = blockIdx.x * 256 + threadIdx.x;
  if (e < E) atomicAdd(&cnt[dst[e]], 1);
}

__global__ __launch_bounds__(256) void scan1_k(
    const int* __restrict__ cnt, int* __restrict__ off,
    int* __restrict__ tot, int n) {
  __shared__ int sh[256];
  int tid = threadIdx.x;
  int i = blockIdx.x * 256 + tid;
  int v = (i < n) ? cnt[i] : 0;
  sh[tid] = v;
  __syncthreads();
  for (int d = 1; d < 256; d <<= 1) {
    int t = (tid >= d) ? sh[tid - d] : 0;
    __syncthreads();
    sh[tid] += t;
    __syncthreads();
  }
  int incl = sh[tid];
  if (i < n) off[i] = incl - v;  // exclusive within chunk
  if (tid == 255) tot[blockIdx.x] = incl;
}

__global__ __launch_bounds__(512) void scan2_k(int* __restrict__ tot, int nt) {
  __shared__ int sh[512];
  int tid = threadIdx.x;
  int v = (tid < nt) ? tot[tid] : 0;
  sh[tid] = v;
  __syncthreads();
  for (int d = 1; d < 512; d <<= 1) {
    int t = (tid >= d) ? sh[tid - d] : 0;
    __syncthreads();
    sh[tid] += t;
    __syncthreads();
  }
  if (tid < nt) tot[tid] = sh[tid] - v;  // exclusive
}

__global__ __launch_bounds__(256) void scan3_k(
    int* __restrict__ off, const int* __restrict__ tot, int n, int total) {
  int i = blockIdx.x * 256 + threadIdx.x;
  if (i < n) off[i] += tot[i >> 8];
  if (i == 0) off[n] = total;
}

__global__ __launch_bounds__(256) void fill_k(
    const int* __restrict__ src, const int* __restrict__ dst,
    const int* __restrict__ off, int* __restrict__ cur,
    int* __restrict__ csr, int E) {
  int e = blockIdx.x * 256 + threadIdx.x;
  if (e < E) {
    int d = dst[e];
    int p = atomicAdd(&cur[d], 1);
    csr[off[d] + p] = src[e];
  }
}

// ---------------------------------------------------------------------------
// Gather-mean aggregation: one wave per dst node, lane owns 2 dims.
// Reads 512B (fp32) / 256B (bf16) per edge, coalesced; writes bf16 mean.
// ---------------------------------------------------------------------------
template <bool SRCF32>
__global__ __launch_bounds__(256) void agg_k(
    const void* __restrict__ featv, const int* __restrict__ off,
    const int* __restrict__ csr, unsigned short* __restrict__ out, int n) {
  int node = blockIdx.x * 4 + (threadIdx.x >> 6);
  int lane = threadIdx.x & 63;
  if (node >= n) return;
  int s0 = off[node], s1 = off[node + 1];
  float a0 = 0.f, a1 = 0.f;
  for (int j = s0; j < s1; ++j) {
    int s = csr[j];
    if (SRCF32) {
      float2 p = *(const float2*)((const float*)featv + (size_t)s * 128 + lane * 2);
      a0 += p.x; a1 += p.y;
    } else {
      const unsigned short* p = (const unsigned short*)featv + (size_t)s * 128 + lane * 2;
      a0 += bf2f(p[0]); a1 += bf2f(p[1]);
    }
  }
  float sc = (s1 > s0) ? 1.f / (float)(s1 - s0) : 0.f;
  unsigned int packed = ((unsigned int)f2bf(a1 * sc) << 16) | f2bf(a0 * sc);
  *(unsigned int*)(out + (size_t)node * 128 + lane * 2) = packed;
}

// ---------------------------------------------------------------------------
// Fused double-GEMM (bf16 MFMA, fp32 accum):
//   out = A1@W[0:128] + A2@W[128:256] + b0 + (deg>0)*be  [, lrelu]
// A1: [M][128] fp32 (layer1 feats) or bf16 (h). A2: [M][128] bf16 (mean agg).
// WT: [N][256] bf16 pre-transposed.  BM=64 rows/block, 256 thr = 4 waves,
// wave w owns cols [w*N/4, (w+1)*N/4).  LDS XOR-swizzled (2-way max).
// ---------------------------------------------------------------------------
template <int N, bool A1F32, bool LRELU, bool OUTBF16>
__global__ __launch_bounds__(256) void gemm_k(
    const void* __restrict__ A1v, const unsigned short* __restrict__ A2,
    const unsigned short* __restrict__ WT, const float* __restrict__ b0,
    const float* __restrict__ be, const int* __restrict__ off,
    void* __restrict__ outv, int M) {
  constexpr int BM = 64;
  constexpr int CPW = N / 4;       // cols per wave
  constexpr int NCF = CPW / 16;    // col frags per wave (2 or 1)
  __shared__ short As[BM * 128];   // 16 KB
  __shared__ short Ws[N * 128];    // 32/16 KB
  __shared__ float degmask[BM];

  const int tid = threadIdx.x;
  const int lane = tid & 63;
  const int wave = tid >> 6;
  const int row0 = blockIdx.x * BM;
  const int colbase = wave * CPW;

  if (tid < BM) {
    int r = row0 + tid;
    degmask[tid] = (r < M && off[r + 1] > off[r]) ? 1.f : 0.f;
  }

  f32x4 acc[4][NCF] = {};

#pragma unroll
  for (int kh = 0; kh < 2; ++kh) {
    __syncthreads();  // also covers degmask before first read
    // stage A tile: 64 rows x 128 bf16 (1024 chunks of 16B)
#pragma unroll
    for (int it = 0; it < 4; ++it) {
      int chunk = tid + it * 256;
      int row = chunk >> 4, c16 = chunk & 15;
      int gr = row0 + row; if (gr > M - 1) gr = M - 1;
      short8 v;
      if (kh == 0 && A1F32) {
        const float* s = (const float*)A1v + (size_t)gr * 128 + c16 * 8;
        float4 x = *(const float4*)s;
        float4 y = *(const float4*)(s + 4);
        v = short8{(short)f2bf(x.x), (short)f2bf(x.y), (short)f2bf(x.z), (short)f2bf(x.w),
                   (short)f2bf(y.x), (short)f2bf(y.y), (short)f2bf(y.z), (short)f2bf(y.w)};
      } else {
        const unsigned short* base = (kh == 0) ? (const unsigned short*)A1v : A2;
        v = *(const short8*)(base + (size_t)gr * 128 + c16 * 8);
      }
      int byteoff = row * 256 + ((c16 * 16) ^ ((row & 7) << 4));
      *(short8*)((char*)As + byteoff) = v;
    }
    // stage W slice: N rows x 128 bf16
#pragma unroll
    for (int it = 0; it < (N * 16) / 256; ++it) {
      int chunk = tid + it * 256;
      int n = chunk >> 4, c16 = chunk & 15;
      short8 v = *(const short8*)(WT + (size_t)n * 256 + kh * 128 + c16 * 8);
      int byteoff = n * 256 + ((c16 * 16) ^ ((n & 7) << 4));
      *(short8*)((char*)Ws + byteoff) = v;
    }
    __syncthreads();

#pragma unroll
    for (int ks = 0; ks < 4; ++ks) {
      short8 af[4];
#pragma unroll
      for (int rf = 0; rf < 4; ++rf) {
        int row = rf * 16 + (lane & 15);
        int c16 = ks * 4 + (lane >> 4);
        int byteoff = row * 256 + ((c16 * 16) ^ ((row & 7) << 4));
        af[rf] = *(const short8*)((const char*)As + byteoff);
      }
      short8 wf[NCF];
#pragma unroll
      for (int cf = 0; cf < NCF; ++cf) {
        int n = colbase + cf * 16 + (lane & 15);
        int c16 = ks * 4 + (lane >> 4);
        int byteoff = n * 256 + ((c16 * 16) ^ ((n & 7) << 4));
        wf[cf] = *(const short8*)((const char*)Ws + byteoff);
      }
#pragma unroll
      for (int rf = 0; rf < 4; ++rf)
#pragma unroll
        for (int cf = 0; cf < NCF; ++cf)
          acc[rf][cf] = __builtin_amdgcn_mfma_f32_16x16x32_bf16(
              af[rf], wf[cf], acc[rf][cf], 0, 0, 0);
    }
  }

  // epilogue: C/D layout col=lane&15, row=(lane>>4)*4+j  [m89 verified]
#pragma unroll
  for (int cf = 0; cf < NCF; ++cf) {
    int c = colbase + cf * 16 + (lane & 15);
    float bb0 = b0[c], bbe = be[c];
#pragma unroll
    for (int rf = 0; rf < 4; ++rf) {
#pragma unroll
      for (int j = 0; j < 4; ++j) {
        int lr = rf * 16 + (lane >> 4) * 4 + j;
        int r = row0 + lr;
        if (r < M) {
          float v = acc[rf][cf][j] + bb0 + degmask[lr] * bbe;
          if (LRELU) v = (v >= 0.f) ? v : 0.01f * v;
          if (OUTBF16)
            ((unsigned short*)outv)[(size_t)r * N + c] = f2bf(v);
          else
            ((float*)outv)[(size_t)r * N + c] = v;
        }
      }
    }
  }
}

extern "C" void kernel_launch(void* const* d_in, const int* in_sizes, int n_in,
                              void* d_out, int out_size, void* d_ws,
                              size_t ws_size, hipStream_t stream) {
  const float* emb_u = (const float*)d_in[0];
  const float* emb_i = (const float*)d_in[1];
  const float* W1_0  = (const float*)d_in[2];
  const float* b1_0  = (const float*)d_in[3];
  const float* W1_ui = (const float*)d_in[4];
  const float* b1_ui = (const float*)d_in[5];
  const float* W1_iu = (const float*)d_in[6];
  const float* b1_iu = (const float*)d_in[7];
  const float* W2_0  = (const float*)d_in[8];
  const float* b2_0  = (const float*)d_in[9];
  const float* W2_ui = (const float*)d_in[10];
  const float* b2_ui = (const float*)d_in[11];
  const float* W2_iu = (const float*)d_in[12];
  const float* b2_iu = (const float*)d_in[13];
  const int* src_ui = (const int*)d_in[14];
  const int* dst_ui = (const int*)d_in[15];
  const int* src_iu = (const int*)d_in[16];
  const int* dst_iu = (const int*)d_in[17];
  float* out = (float*)d_out;

  // ---- workspace layout ----
  char* p = (char*)d_ws;
  unsigned short* WT1i = (unsigned short*)p; p += 65536;
  unsigned short* WT1u = (unsigned short*)p; p += 65536;
  unsigned short* WT2i = (unsigned short*)p; p += 32768;
  unsigned short* WT2u = (unsigned short*)p; p += 32768;
  int* off_ui = (int*)p; p += 400128;          // 100001 ints padded
  int* off_iu = (int*)p; p += 400128;
  int* csr_ui = (int*)p; p += 2000000;
  int* csr_iu = (int*)p; p += 2000000;
  int* tot_ui = (int*)p; p += 2048;            // 391 ints padded
  int* tot_iu = (int*)p; p += 2048;
  const size_t FB = (size_t)N_USER * 128 * 2;  // 25.6 MB bf16 buffer
  unsigned short* hu   = (unsigned short*)p; p += FB;
  unsigned short* hi   = (unsigned short*)p; p += FB;
  unsigned short* aggA = (unsigned short*)p; p += FB;
  unsigned short* aggB = (unsigned short*)p; p += FB;
  // cursors alias aggA (only live before first agg write)
  int* cur_i = (int*)aggA;
  int* cur_u = cur_i + N_ITEM;

  const int EB = (NEDGE + 255) / 256;          // 1954
  const int NB = (N_USER + 255) / 256;         // 391
  const int GG = (N_USER + 63) / 64;           // 1563 gemm blocks

  // weight prep + CSR build (graph identical for both layers)
  prep_wt_k<<<384, 256, 0, stream>>>(W1_0, W1_ui, W1_iu, W2_0, W2_ui, W2_iu,
                                     WT1i, WT1u, WT2i, WT2u);
  hipMemsetAsync(cur_i, 0, 2 * N_USER * sizeof(int), stream);
  count_k<<<EB, 256, 0, stream>>>(dst_ui, cur_i, NEDGE);
  count_k<<<EB, 256, 0, stream>>>(dst_iu, cur_u, NEDGE);
  scan1_k<<<NB, 256, 0, stream>>>(cur_i, off_ui, tot_ui, N_ITEM);
  scan1_k<<<NB, 256, 0, stream>>>(cur_u, off_iu, tot_iu, N_USER);
  scan2_k<<<1, 512, 0, stream>>>(tot_ui, NB);
  scan2_k<<<1, 512, 0, stream>>>(tot_iu, NB);
  scan3_k<<<NB, 256, 0, stream>>>(off_ui, tot_ui, N_ITEM, NEDGE);
  scan3_k<<<NB, 256, 0, stream>>>(off_iu, tot_iu, N_USER, NEDGE);
  hipMemsetAsync(cur_i, 0, 2 * N_USER * sizeof(int), stream);
  fill_k<<<EB, 256, 0, stream>>>(src_ui, dst_ui, off_ui, cur_i, csr_ui, NEDGE);
  fill_k<<<EB, 256, 0, stream>>>(src_iu, dst_iu, off_iu, cur_u, csr_iu, NEDGE);

  // ---- layer 1: agg raw feats, fused double-GEMM + lrelu -> bf16 h ----
  agg_k<true><<<25000, 256, 0, stream>>>(emb_u, off_ui, csr_ui, aggA, N_ITEM);
  agg_k<true><<<25000, 256, 0, stream>>>(emb_i, off_iu, csr_iu, aggB, N_USER);
  gemm_k<128, true, true, true><<<GG, 256, 0, stream>>>(
      emb_i, aggA, WT1i, b1_0, b1_ui, off_ui, hi, N_ITEM);
  gemm_k<128, true, true, true><<<GG, 256, 0, stream>>>(
      emb_u, aggB, WT1u, b1_0, b1_iu, off_iu, hu, N_USER);

  // ---- layer 2: agg h (bf16), fused double-GEMM -> fp32 d_out ----
  agg_k<false><<<25000, 256, 0, stream>>>(hu, off_ui, csr_ui, aggA, N_ITEM);
  agg_k<false><<<25000, 256, 0, stream>>>(hi, off_iu, csr_iu, aggB, N_USER);
  gemm_k<64, false, false, false><<<GG, 256, 0, stream>>>(
      hi, aggA, WT2i, b2_0, b2_ui, off_ui, out + (size_t)N_USER * 64, N_ITEM);
  gemm_k<64, false, false, false><<<GG, 256, 0, stream>>>(
      hu, aggB, WT2u, b2_0, b2_iu, off_iu, out, N_USER);
}

// Round 3
// 310.455 us; speedup vs baseline: 4.2051x; 1.4787x over previous
//
#include <hip/hip_runtime.h>

#define N_USER 100000
#define N_ITEM 100000
#define NEDGE  500000

typedef __attribute__((ext_vector_type(8))) short short8;
typedef __attribute__((ext_vector_type(4))) float f32x4;

__device__ __forceinline__ unsigned short f2bf(float f) {
  union { float f; unsigned int u; } x{f};
  unsigned int r = x.u + 0x7fffu + ((x.u >> 16) & 1u);  // RTN-even
  return (unsigned short)(r >> 16);
}
__device__ __forceinline__ float bf2f(unsigned short u) {
  union { unsigned int u; float f; } x{(unsigned int)u << 16};
  return x.f;
}

// ---------------------------------------------------------------------------
// Weight prep: 4 fused transposed bf16 weight buffers, [N][256] with
// k<128 from W0 and k>=128 from We.
// ---------------------------------------------------------------------------
__global__ __launch_bounds__(256) void prep_wt_k(
    const float* __restrict__ W10, const float* __restrict__ W1ui,
    const float* __restrict__ W1iu, const float* __restrict__ W20,
    const float* __restrict__ W2ui, const float* __restrict__ W2iu,
    unsigned short* __restrict__ WT1i, unsigned short* __restrict__ WT1u,
    unsigned short* __restrict__ WT2i, unsigned short* __restrict__ WT2u) {
  int t = blockIdx.x * 256 + threadIdx.x;
  if (t < 32768) {
    int n = t >> 8, k = t & 255;
    float v = (k < 128) ? W10[k * 128 + n] : W1ui[(k - 128) * 128 + n];
    WT1i[t] = f2bf(v);
  } else if (t < 65536) {
    int q = t - 32768; int n = q >> 8, k = q & 255;
    float v = (k < 128) ? W10[k * 128 + n] : W1iu[(k - 128) * 128 + n];
    WT1u[q] = f2bf(v);
  } else if (t < 81920) {
    int q = t - 65536; int n = q >> 8, k = q & 255;
    float v = (k < 128) ? W20[k * 64 + n] : W2ui[(k - 128) * 64 + n];
    WT2i[q] = f2bf(v);
  } else if (t < 98304) {
    int q = t - 81920; int n = q >> 8, k = q & 255;
    float v = (k < 128) ? W20[k * 64 + n] : W2iu[(k - 128) * 64 + n];
    WT2u[q] = f2bf(v);
  }
}

// ---------------------------------------------------------------------------
// CSR build (both graphs in each dispatch via grid split).
// ---------------------------------------------------------------------------
__global__ __launch_bounds__(256) void count2_k(
    const int* __restrict__ dstA, int* __restrict__ cntA,
    const int* __restrict__ dstB, int* __restrict__ cntB, int E, int nbA) {
  int b = blockIdx.x;
  const int* dst; int* cnt;
  if (b < nbA) { dst = dstA; cnt = cntA; } else { b -= nbA; dst = dstB; cnt = cntB; }
  int e = b * 256 + threadIdx.x;
  if (e < E) atomicAdd(&cnt[dst[e]], 1);
}

__global__ __launch_bounds__(256) void scan1m_k(
    const int* __restrict__ cntA, int* __restrict__ offA, int* __restrict__ totA,
    const int* __restrict__ cntB, int* __restrict__ offB, int* __restrict__ totB,
    int n, int nbA) {
  __shared__ int sh[256];
  int b = blockIdx.x;
  const int* cnt; int* off; int* tot;
  if (b < nbA) { cnt = cntA; off = offA; tot = totA; }
  else { b -= nbA; cnt = cntB; off = offB; tot = totB; }
  int tid = threadIdx.x;
  int i = b * 256 + tid;
  int v = (i < n) ? cnt[i] : 0;
  sh[tid] = v;
  __syncthreads();
  for (int d = 1; d < 256; d <<= 1) {
    int t = (tid >= d) ? sh[tid - d] : 0;
    __syncthreads();
    sh[tid] += t;
    __syncthreads();
  }
  int incl = sh[tid];
  if (i < n) off[i] = incl - v;
  if (tid == 255) tot[b] = incl;
}

__global__ __launch_bounds__(512) void scan2m_k(
    int* __restrict__ totA, int* __restrict__ totB, int nt) {
  __shared__ int sh[512];
  int* tot = (blockIdx.x == 0) ? totA : totB;
  int tid = threadIdx.x;
  int v = (tid < nt) ? tot[tid] : 0;
  sh[tid] = v;
  __syncthreads();
  for (int d = 1; d < 512; d <<= 1) {
    int t = (tid >= d) ? sh[tid - d] : 0;
    __syncthreads();
    sh[tid] += t;
    __syncthreads();
  }
  if (tid < nt) tot[tid] = sh[tid] - v;
}

__global__ __launch_bounds__(256) void scan3m_k(
    int* __restrict__ offA, const int* __restrict__ totA,
    int* __restrict__ offB, const int* __restrict__ totB,
    int n, int total, int nbA) {
  int b = blockIdx.x;
  int* off; const int* tot;
  if (b < nbA) { off = offA; tot = totA; } else { b -= nbA; off = offB; tot = totB; }
  int i = b * 256 + threadIdx.x;
  if (i < n) off[i] += tot[i >> 8];
  if (i == 0) off[n] = total;
}

__global__ __launch_bounds__(256) void fill2_k(
    const int* __restrict__ srcA, const int* __restrict__ dstA,
    const int* __restrict__ offA, int* __restrict__ curA, int* __restrict__ csrA,
    const int* __restrict__ srcB, const int* __restrict__ dstB,
    const int* __restrict__ offB, int* __restrict__ curB, int* __restrict__ csrB,
    int E, int nbA) {
  int b = blockIdx.x;
  const int *src, *dst, *off; int *cur, *csr;
  if (b < nbA) { src = srcA; dst = dstA; off = offA; cur = curA; csr = csrA; }
  else { b -= nbA; src = srcB; dst = dstB; off = offB; cur = curB; csr = csrB; }
  int e = b * 256 + threadIdx.x;
  if (e < E) {
    int d = dst[e];
    int p = atomicAdd(&cur[d], 1);
    csr[off[d] + p] = src[e];
  }
}

// ---------------------------------------------------------------------------
// Gather-mean aggregation, both directions in one dispatch.
// fp32 src: 32 lanes/node (float4/lane), 8 nodes/block.
// bf16 src: 16 lanes/node (short8/lane), 16 nodes/block.
// Edge loop unrolled x4 with independent loads (latency hiding).
// ---------------------------------------------------------------------------
template <bool SRCF32>
__global__ __launch_bounds__(256) void agg2_k(
    const void* __restrict__ featA, const int* __restrict__ offA,
    const int* __restrict__ csrA, unsigned short* __restrict__ outA,
    const void* __restrict__ featB, const int* __restrict__ offB,
    const int* __restrict__ csrB, unsigned short* __restrict__ outB,
    int nbA) {
  constexpr int LPN = SRCF32 ? 32 : 16;
  constexpr int NPB = 256 / LPN;
  int b = blockIdx.x;
  const void* feat; const int* off; const int* csr; unsigned short* out;
  if (b < nbA) { feat = featA; off = offA; csr = csrA; out = outA; }
  else { b -= nbA; feat = featB; off = offB; csr = csrB; out = outB; }
  int node = b * NPB + threadIdx.x / LPN;
  int ln = threadIdx.x % LPN;
  int s0 = off[node], s1 = off[node + 1];

  if (SRCF32) {
    const float* f = (const float*)feat;
    float4 a = {0.f, 0.f, 0.f, 0.f};
    int j = s0;
    for (; j + 4 <= s1; j += 4) {
      int i0 = csr[j], i1 = csr[j + 1], i2 = csr[j + 2], i3 = csr[j + 3];
      float4 v0 = *(const float4*)(f + (size_t)i0 * 128 + ln * 4);
      float4 v1 = *(const float4*)(f + (size_t)i1 * 128 + ln * 4);
      float4 v2 = *(const float4*)(f + (size_t)i2 * 128 + ln * 4);
      float4 v3 = *(const float4*)(f + (size_t)i3 * 128 + ln * 4);
      a.x += (v0.x + v1.x) + (v2.x + v3.x);
      a.y += (v0.y + v1.y) + (v2.y + v3.y);
      a.z += (v0.z + v1.z) + (v2.z + v3.z);
      a.w += (v0.w + v1.w) + (v2.w + v3.w);
    }
    for (; j < s1; ++j) {
      float4 v = *(const float4*)(f + (size_t)csr[j] * 128 + ln * 4);
      a.x += v.x; a.y += v.y; a.z += v.z; a.w += v.w;
    }
    float sc = (s1 > s0) ? 1.f / (float)(s1 - s0) : 0.f;
    unsigned int p0 = ((unsigned int)f2bf(a.y * sc) << 16) | f2bf(a.x * sc);
    unsigned int p1 = ((unsigned int)f2bf(a.w * sc) << 16) | f2bf(a.z * sc);
    uint2 pk{p0, p1};
    *(uint2*)(out + (size_t)node * 128 + ln * 4) = pk;
  } else {
    const unsigned short* f = (const unsigned short*)feat;
    float a[8] = {0, 0, 0, 0, 0, 0, 0, 0};
    int j = s0;
    for (; j + 4 <= s1; j += 4) {
      int i0 = csr[j], i1 = csr[j + 1], i2 = csr[j + 2], i3 = csr[j + 3];
      short8 v0 = *(const short8*)(f + (size_t)i0 * 128 + ln * 8);
      short8 v1 = *(const short8*)(f + (size_t)i1 * 128 + ln * 8);
      short8 v2 = *(const short8*)(f + (size_t)i2 * 128 + ln * 8);
      short8 v3 = *(const short8*)(f + (size_t)i3 * 128 + ln * 8);
#pragma unroll
      for (int d = 0; d < 8; ++d)
        a[d] += (bf2f((unsigned short)v0[d]) + bf2f((unsigned short)v1[d])) +
                (bf2f((unsigned short)v2[d]) + bf2f((unsigned short)v3[d]));
    }
    for (; j < s1; ++j) {
      short8 v = *(const short8*)(f + (size_t)csr[j] * 128 + ln * 8);
#pragma unroll
      for (int d = 0; d < 8; ++d) a[d] += bf2f((unsigned short)v[d]);
    }
    float sc = (s1 > s0) ? 1.f / (float)(s1 - s0) : 0.f;
    short8 pk;
#pragma unroll
    for (int d = 0; d < 8; ++d) pk[d] = (short)f2bf(a[d] * sc);
    *(short8*)(out + (size_t)node * 128 + ln * 8) = pk;
  }
}

// ---------------------------------------------------------------------------
// Fused double-GEMM (bf16 MFMA, fp32 accum), both ntypes in one dispatch:
//   out = A1@W[0:128] + A2@W[128:256] + b0 + (deg>0)*be  [, lrelu]
// ---------------------------------------------------------------------------
template <int N, bool A1F32, bool LRELU, bool OUTBF16>
__global__ __launch_bounds__(256) void gemm2_k(
    const void* __restrict__ A1a, const unsigned short* __restrict__ A2a,
    const unsigned short* __restrict__ WTa, const float* __restrict__ b0a,
    const float* __restrict__ bea, const int* __restrict__ offa,
    void* __restrict__ outa,
    const void* __restrict__ A1b, const unsigned short* __restrict__ A2b,
    const unsigned short* __restrict__ WTb, const float* __restrict__ b0b,
    const float* __restrict__ beb, const int* __restrict__ offb,
    void* __restrict__ outb, int M, int nbA) {
  constexpr int BM = 64;
  constexpr int CPW = N / 4;
  constexpr int NCF = CPW / 16;
  __shared__ short As[BM * 128];
  __shared__ short Ws[N * 128];
  __shared__ float degmask[BM];

  int blk = blockIdx.x;
  const void* A1v; const unsigned short* A2; const unsigned short* WT;
  const float* b0; const float* be; const int* off; void* outv;
  if (blk < nbA) { A1v = A1a; A2 = A2a; WT = WTa; b0 = b0a; be = bea; off = offa; outv = outa; }
  else { blk -= nbA; A1v = A1b; A2 = A2b; WT = WTb; b0 = b0b; be = beb; off = offb; outv = outb; }

  const int tid = threadIdx.x;
  const int lane = tid & 63;
  const int wave = tid >> 6;
  const int row0 = blk * BM;
  const int colbase = wave * CPW;

  if (tid < BM) {
    int r = row0 + tid;
    degmask[tid] = (r < M && off[r + 1] > off[r]) ? 1.f : 0.f;
  }

  f32x4 acc[4][NCF] = {};

#pragma unroll
  for (int kh = 0; kh < 2; ++kh) {
    __syncthreads();
#pragma unroll
    for (int it = 0; it < 4; ++it) {
      int chunk = tid + it * 256;
      int row = chunk >> 4, c16 = chunk & 15;
      int gr = row0 + row; if (gr > M - 1) gr = M - 1;
      short8 v;
      if (kh == 0 && A1F32) {
        const float* s = (const float*)A1v + (size_t)gr * 128 + c16 * 8;
        float4 x = *(const float4*)s;
        float4 y = *(const float4*)(s + 4);
        v = short8{(short)f2bf(x.x), (short)f2bf(x.y), (short)f2bf(x.z), (short)f2bf(x.w),
                   (short)f2bf(y.x), (short)f2bf(y.y), (short)f2bf(y.z), (short)f2bf(y.w)};
      } else {
        const unsigned short* base = (kh == 0) ? (const unsigned short*)A1v : A2;
        v = *(const short8*)(base + (size_t)gr * 128 + c16 * 8);
      }
      int byteoff = row * 256 + ((c16 * 16) ^ ((row & 7) << 4));
      *(short8*)((char*)As + byteoff) = v;
    }
#pragma unroll
    for (int it = 0; it < (N * 16) / 256; ++it) {
      int chunk = tid + it * 256;
      int n = chunk >> 4, c16 = chunk & 15;
      short8 v = *(const short8*)(WT + (size_t)n * 256 + kh * 128 + c16 * 8);
      int byteoff = n * 256 + ((c16 * 16) ^ ((n & 7) << 4));
      *(short8*)((char*)Ws + byteoff) = v;
    }
    __syncthreads();

#pragma unroll
    for (int ks = 0; ks < 4; ++ks) {
      short8 af[4];
#pragma unroll
      for (int rf = 0; rf < 4; ++rf) {
        int row = rf * 16 + (lane & 15);
        int c16 = ks * 4 + (lane >> 4);
        int byteoff = row * 256 + ((c16 * 16) ^ ((row & 7) << 4));
        af[rf] = *(const short8*)((const char*)As + byteoff);
      }
      short8 wf[NCF];
#pragma unroll
      for (int cf = 0; cf < NCF; ++cf) {
        int n = colbase + cf * 16 + (lane & 15);
        int c16 = ks * 4 + (lane >> 4);
        int byteoff = n * 256 + ((c16 * 16) ^ ((n & 7) << 4));
        wf[cf] = *(const short8*)((const char*)Ws + byteoff);
      }
#pragma unroll
      for (int rf = 0; rf < 4; ++rf)
#pragma unroll
        for (int cf = 0; cf < NCF; ++cf)
          acc[rf][cf] = __builtin_amdgcn_mfma_f32_16x16x32_bf16(
              af[rf], wf[cf], acc[rf][cf], 0, 0, 0);
    }
  }

#pragma unroll
  for (int cf = 0; cf < NCF; ++cf) {
    int c = colbase + cf * 16 + (lane & 15);
    float bb0 = b0[c], bbe = be[c];
#pragma unroll
    for (int rf = 0; rf < 4; ++rf) {
#pragma unroll
      for (int j = 0; j < 4; ++j) {
        int lr = rf * 16 + (lane >> 4) * 4 + j;
        int r = row0 + lr;
        if (r < M) {
          float v = acc[rf][cf][j] + bb0 + degmask[lr] * bbe;
          if (LRELU) v = (v >= 0.f) ? v : 0.01f * v;
          if (OUTBF16)
            ((unsigned short*)outv)[(size_t)r * N + c] = f2bf(v);
          else
            ((float*)outv)[(size_t)r * N + c] = v;
        }
      }
    }
  }
}

extern "C" void kernel_launch(void* const* d_in, const int* in_sizes, int n_in,
                              void* d_out, int out_size, void* d_ws,
                              size_t ws_size, hipStream_t stream) {
  const float* emb_u = (const float*)d_in[0];
  const float* emb_i = (const float*)d_in[1];
  const float* W1_0  = (const float*)d_in[2];
  const float* b1_0  = (const float*)d_in[3];
  const float* W1_ui = (const float*)d_in[4];
  const float* b1_ui = (const float*)d_in[5];
  const float* W1_iu = (const float*)d_in[6];
  const float* b1_iu = (const float*)d_in[7];
  const float* W2_0  = (const float*)d_in[8];
  const float* b2_0  = (const float*)d_in[9];
  const float* W2_ui = (const float*)d_in[10];
  const float* b2_ui = (const float*)d_in[11];
  const float* W2_iu = (const float*)d_in[12];
  const float* b2_iu = (const float*)d_in[13];
  const int* src_ui = (const int*)d_in[14];
  const int* dst_ui = (const int*)d_in[15];
  const int* src_iu = (const int*)d_in[16];
  const int* dst_iu = (const int*)d_in[17];
  float* out = (float*)d_out;

  // ---- workspace layout ----
  char* p = (char*)d_ws;
  unsigned short* WT1i = (unsigned short*)p; p += 65536;
  unsigned short* WT1u = (unsigned short*)p; p += 65536;
  unsigned short* WT2i = (unsigned short*)p; p += 32768;
  unsigned short* WT2u = (unsigned short*)p; p += 32768;
  int* off_ui = (int*)p; p += 400128;
  int* off_iu = (int*)p; p += 400128;
  int* csr_ui = (int*)p; p += 2000000;
  int* csr_iu = (int*)p; p += 2000000;
  int* tot_ui = (int*)p; p += 2048;
  int* tot_iu = (int*)p; p += 2048;
  const size_t FB = (size_t)N_USER * 128 * 2;
  unsigned short* hu   = (unsigned short*)p; p += FB;
  unsigned short* hi   = (unsigned short*)p; p += FB;
  unsigned short* aggA = (unsigned short*)p; p += FB;
  unsigned short* aggB = (unsigned short*)p; p += FB;
  int* cur_i = (int*)aggA;  // cursors alias aggA (dead once agg runs)
  int* cur_u = cur_i + N_ITEM;

  const int EB = (NEDGE + 255) / 256;   // 1954
  const int NB = (N_USER + 255) / 256;  // 391
  const int GG = (N_USER + 63) / 64;    // 1563

  prep_wt_k<<<384, 256, 0, stream>>>(W1_0, W1_ui, W1_iu, W2_0, W2_ui, W2_iu,
                                     WT1i, WT1u, WT2i, WT2u);
  hipMemsetAsync(cur_i, 0, 2 * N_USER * sizeof(int), stream);
  count2_k<<<2 * EB, 256, 0, stream>>>(dst_ui, cur_i, dst_iu, cur_u, NEDGE, EB);
  scan1m_k<<<2 * NB, 256, 0, stream>>>(cur_i, off_ui, tot_ui, cur_u, off_iu,
                                       tot_iu, N_USER, NB);
  scan2m_k<<<2, 512, 0, stream>>>(tot_ui, tot_iu, NB);
  scan3m_k<<<2 * NB, 256, 0, stream>>>(off_ui, tot_ui, off_iu, tot_iu, N_USER,
                                       NEDGE, NB);
  hipMemsetAsync(cur_i, 0, 2 * N_USER * sizeof(int), stream);
  fill2_k<<<2 * EB, 256, 0, stream>>>(src_ui, dst_ui, off_ui, cur_i, csr_ui,
                                      src_iu, dst_iu, off_iu, cur_u, csr_iu,
                                      NEDGE, EB);

  // ---- layer 1: agg raw fp32 feats (both dirs), fused GEMM+lrelu ----
  agg2_k<true><<<2 * 12500, 256, 0, stream>>>(
      emb_u, off_ui, csr_ui, aggA, emb_i, off_iu, csr_iu, aggB, 12500);
  gemm2_k<128, true, true, true><<<2 * GG, 256, 0, stream>>>(
      emb_i, aggA, WT1i, b1_0, b1_ui, off_ui, hi,
      emb_u, aggB, WT1u, b1_0, b1_iu, off_iu, hu, N_USER, GG);

  // ---- layer 2: agg bf16 h (both dirs), fused GEMM -> fp32 d_out ----
  agg2_k<false><<<2 * 6250, 256, 0, stream>>>(
      hu, off_ui, csr_ui, aggA, hi, off_iu, csr_iu, aggB, 6250);
  gemm2_k<64, false, false, false><<<2 * GG, 256, 0, stream>>>(
      hi, aggA, WT2i, b2_0, b2_ui, off_ui, out + (size_t)N_USER * 64,
      hu, aggB, WT2u, b2_0, b2_iu, off_iu, out, N_USER, GG);
}

// Round 4
// 282.546 us; speedup vs baseline: 4.6204x; 1.0988x over previous
//
#include <hip/hip_runtime.h>

#define N_USER 100000
#define N_ITEM 100000
#define NEDGE  500000

typedef __attribute__((ext_vector_type(8))) short short8;
typedef __attribute__((ext_vector_type(4))) float f32x4;

__device__ __forceinline__ unsigned short f2bf(float f) {
  union { float f; unsigned int u; } x{f};
  unsigned int r = x.u + 0x7fffu + ((x.u >> 16) & 1u);  // RTN-even
  return (unsigned short)(r >> 16);
}
__device__ __forceinline__ float bf2f(unsigned short u) {
  union { unsigned int u; float f; } x{(unsigned int)u << 16};
  return x.f;
}

// ---------------------------------------------------------------------------
// setup_k (grid-split): [0,384) weight prep -> 4 fused transposed bf16 W
// buffers [N][256] (k<128 from W0, k>=128 from We); [384,12884) emb fp32->bf16
// conversion; [12884,16792) edge degree count (cnt pre-zeroed by memset).
// ---------------------------------------------------------------------------
__global__ __launch_bounds__(256) void setup_k(
    const float* __restrict__ W10, const float* __restrict__ W1ui,
    const float* __restrict__ W1iu, const float* __restrict__ W20,
    const float* __restrict__ W2ui, const float* __restrict__ W2iu,
    unsigned short* __restrict__ WT1i, unsigned short* __restrict__ WT1u,
    unsigned short* __restrict__ WT2i, unsigned short* __restrict__ WT2u,
    const float* __restrict__ emb_u, const float* __restrict__ emb_i,
    unsigned short* __restrict__ ebu, unsigned short* __restrict__ ebi,
    const int* __restrict__ dst_ui, int* __restrict__ cnt_i,
    const int* __restrict__ dst_iu, int* __restrict__ cnt_u) {
  int b = blockIdx.x, tid = threadIdx.x;
  if (b < 384) {
    int t = b * 256 + tid;  // 0..98303
    if (t < 32768) {
      int n = t >> 8, k = t & 255;
      float v = (k < 128) ? W10[k * 128 + n] : W1ui[(k - 128) * 128 + n];
      WT1i[t] = f2bf(v);
    } else if (t < 65536) {
      int q = t - 32768; int n = q >> 8, k = q & 255;
      float v = (k < 128) ? W10[k * 128 + n] : W1iu[(k - 128) * 128 + n];
      WT1u[q] = f2bf(v);
    } else if (t < 81920) {
      int q = t - 65536; int n = q >> 8, k = q & 255;
      float v = (k < 128) ? W20[k * 64 + n] : W2ui[(k - 128) * 64 + n];
      WT2i[q] = f2bf(v);
    } else {
      int q = t - 81920; int n = q >> 8, k = q & 255;
      float v = (k < 128) ? W20[k * 64 + n] : W2iu[(k - 128) * 64 + n];
      WT2u[q] = f2bf(v);
    }
  } else if (b < 12884) {
    int blk = b - 384;
    const float* src; unsigned short* dstp;
    if (blk < 6250) { src = emb_u; dstp = ebu; }
    else { blk -= 6250; src = emb_i; dstp = ebi; }
    size_t base = (size_t)blk * 2048 + (size_t)tid * 8;
    float4 x = *(const float4*)(src + base);
    float4 y = *(const float4*)(src + base + 4);
    short8 v{(short)f2bf(x.x), (short)f2bf(x.y), (short)f2bf(x.z), (short)f2bf(x.w),
             (short)f2bf(y.x), (short)f2bf(y.y), (short)f2bf(y.z), (short)f2bf(y.w)};
    *(short8*)(dstp + base) = v;
  } else {
    int eb = b - 12884;
    const int* dst; int* cnt;
    if (eb < 1954) { dst = dst_ui; cnt = cnt_i; }
    else { eb -= 1954; dst = dst_iu; cnt = cnt_u; }
    int e = eb * 256 + tid;
    if (e < NEDGE) atomicAdd(&cnt[dst[e]], 1);
  }
}

// ---------------------------------------------------------------------------
// CSR scans + fill (both graphs per dispatch via grid split).
// ---------------------------------------------------------------------------
__global__ __launch_bounds__(256) void scan1m_k(
    const int* __restrict__ cntA, int* __restrict__ offA, int* __restrict__ totA,
    const int* __restrict__ cntB, int* __restrict__ offB, int* __restrict__ totB,
    int n, int nbA) {
  __shared__ int sh[256];
  int b = blockIdx.x;
  const int* cnt; int* off; int* tot;
  if (b < nbA) { cnt = cntA; off = offA; tot = totA; }
  else { b -= nbA; cnt = cntB; off = offB; tot = totB; }
  int tid = threadIdx.x;
  int i = b * 256 + tid;
  int v = (i < n) ? cnt[i] : 0;
  sh[tid] = v;
  __syncthreads();
  for (int d = 1; d < 256; d <<= 1) {
    int t = (tid >= d) ? sh[tid - d] : 0;
    __syncthreads();
    sh[tid] += t;
    __syncthreads();
  }
  int incl = sh[tid];
  if (i < n) off[i] = incl - v;
  if (tid == 255) tot[b] = incl;
}

__global__ __launch_bounds__(512) void scan2m_k(
    int* __restrict__ totA, int* __restrict__ totB, int nt) {
  __shared__ int sh[512];
  int* tot = (blockIdx.x == 0) ? totA : totB;
  int tid = threadIdx.x;
  int v = (tid < nt) ? tot[tid] : 0;
  sh[tid] = v;
  __syncthreads();
  for (int d = 1; d < 512; d <<= 1) {
    int t = (tid >= d) ? sh[tid - d] : 0;
    __syncthreads();
    sh[tid] += t;
    __syncthreads();
  }
  if (tid < nt) tot[tid] = sh[tid] - v;
}

__global__ __launch_bounds__(256) void scan3m_k(
    int* __restrict__ offA, const int* __restrict__ totA,
    int* __restrict__ offB, const int* __restrict__ totB,
    int n, int total, int nbA) {
  int b = blockIdx.x;
  int* off; const int* tot;
  if (b < nbA) { off = offA; tot = totA; } else { b -= nbA; off = offB; tot = totB; }
  int i = b * 256 + threadIdx.x;
  if (i < n) off[i] += tot[i >> 8];
  if (i == 0) off[n] = total;
}

__global__ __launch_bounds__(256) void fill2_k(
    const int* __restrict__ srcA, const int* __restrict__ dstA,
    const int* __restrict__ offA, int* __restrict__ curA, int* __restrict__ csrA,
    const int* __restrict__ srcB, const int* __restrict__ dstB,
    const int* __restrict__ offB, int* __restrict__ curB, int* __restrict__ csrB,
    int E, int nbA) {
  int b = blockIdx.x;
  const int *src, *dst, *off; int *cur, *csr;
  if (b < nbA) { src = srcA; dst = dstA; off = offA; cur = curA; csr = csrA; }
  else { b -= nbA; src = srcB; dst = dstB; off = offB; cur = curB; csr = csrB; }
  int e = b * 256 + threadIdx.x;
  if (e < E) {
    int d = dst[e];
    int p = atomicAdd(&cur[d], 1);
    csr[off[d] + p] = src[e];
  }
}

// ---------------------------------------------------------------------------
// Gather-mean aggregation (bf16 src, 128-dim), both directions per dispatch.
// 16 lanes/node (short8/lane), 16 nodes/block. Edge loop unrolled x4 with
// next-group index prefetch (software pipeline).
// ---------------------------------------------------------------------------
__global__ __launch_bounds__(256) void agg2_k(
    const unsigned short* __restrict__ featA, const int* __restrict__ offA,
    const int* __restrict__ csrA, unsigned short* __restrict__ outA,
    const unsigned short* __restrict__ featB, const int* __restrict__ offB,
    const int* __restrict__ csrB, unsigned short* __restrict__ outB,
    int nbA) {
  int b = blockIdx.x;
  const unsigned short* feat; const int* off; const int* csr; unsigned short* out;
  if (b < nbA) { feat = featA; off = offA; csr = csrA; out = outA; }
  else { b -= nbA; feat = featB; off = offB; csr = csrB; out = outB; }
  int node = b * 16 + (threadIdx.x >> 4);
  int ln = threadIdx.x & 15;
  int s0 = off[node], s1 = off[node + 1];
  float a[8] = {0, 0, 0, 0, 0, 0, 0, 0};
  int j = s0;
  if (j + 4 <= s1) {
    int i0 = csr[j], i1 = csr[j + 1], i2 = csr[j + 2], i3 = csr[j + 3];
    for (;;) {
      bool more = (j + 8 <= s1);
      int n0, n1, n2, n3;
      if (more) { n0 = csr[j + 4]; n1 = csr[j + 5]; n2 = csr[j + 6]; n3 = csr[j + 7]; }
      short8 v0 = *(const short8*)(feat + (size_t)i0 * 128 + ln * 8);
      short8 v1 = *(const short8*)(feat + (size_t)i1 * 128 + ln * 8);
      short8 v2 = *(const short8*)(feat + (size_t)i2 * 128 + ln * 8);
      short8 v3 = *(const short8*)(feat + (size_t)i3 * 128 + ln * 8);
#pragma unroll
      for (int d = 0; d < 8; ++d)
        a[d] += (bf2f((unsigned short)v0[d]) + bf2f((unsigned short)v1[d])) +
                (bf2f((unsigned short)v2[d]) + bf2f((unsigned short)v3[d]));
      j += 4;
      if (!more) break;
      i0 = n0; i1 = n1; i2 = n2; i3 = n3;
    }
  }
  if (j + 2 <= s1) {
    int i0 = csr[j], i1 = csr[j + 1];
    short8 v0 = *(const short8*)(feat + (size_t)i0 * 128 + ln * 8);
    short8 v1 = *(const short8*)(feat + (size_t)i1 * 128 + ln * 8);
#pragma unroll
    for (int d = 0; d < 8; ++d)
      a[d] += bf2f((unsigned short)v0[d]) + bf2f((unsigned short)v1[d]);
    j += 2;
  }
  if (j < s1) {
    short8 v = *(const short8*)(feat + (size_t)csr[j] * 128 + ln * 8);
#pragma unroll
    for (int d = 0; d < 8; ++d) a[d] += bf2f((unsigned short)v[d]);
  }
  float sc = (s1 > s0) ? 1.f / (float)(s1 - s0) : 0.f;
  short8 pk;
#pragma unroll
  for (int d = 0; d < 8; ++d) pk[d] = (short)f2bf(a[d] * sc);
  *(short8*)(out + (size_t)node * 128 + ln * 8) = pk;
}

// ---------------------------------------------------------------------------
// Fused double-GEMM (bf16 MFMA, fp32 accum), both ntypes per dispatch:
//   out = A1@W[0:128] + A2@W[128:256] + b0 + (deg>0)*be  [, lrelu]
// A1, A2: [M][128] bf16. WT: [N][256] bf16 pre-transposed.
// BM=64, 256 thr = 4 waves, wave w owns cols [w*N/4,(w+1)*N/4).
// LDS XOR-swizzled (2-way max conflict). In-place out==A1 is safe
// (row-disjoint blocks; stage-read precedes epilogue-write within block).
// ---------------------------------------------------------------------------
template <int N, bool LRELU, bool OUTBF16>
__global__ __launch_bounds__(256) void gemm2_k(
    const unsigned short* __restrict__ A1a, const unsigned short* __restrict__ A2a,
    const unsigned short* __restrict__ WTa, const float* __restrict__ b0a,
    const float* __restrict__ bea, const int* __restrict__ offa,
    void* __restrict__ outa,
    const unsigned short* __restrict__ A1b, const unsigned short* __restrict__ A2b,
    const unsigned short* __restrict__ WTb, const float* __restrict__ b0b,
    const float* __restrict__ beb, const int* __restrict__ offb,
    void* __restrict__ outb, int M, int nbA) {
  constexpr int BM = 64;
  constexpr int CPW = N / 4;
  constexpr int NCF = CPW / 16;
  __shared__ short As[BM * 128];
  __shared__ short Ws[N * 128];
  __shared__ float degmask[BM];

  int blk = blockIdx.x;
  const unsigned short* A1; const unsigned short* A2; const unsigned short* WT;
  const float* b0; const float* be; const int* off; void* outv;
  if (blk < nbA) { A1 = A1a; A2 = A2a; WT = WTa; b0 = b0a; be = bea; off = offa; outv = outa; }
  else { blk -= nbA; A1 = A1b; A2 = A2b; WT = WTb; b0 = b0b; be = beb; off = offb; outv = outb; }

  const int tid = threadIdx.x;
  const int lane = tid & 63;
  const int wave = tid >> 6;
  const int row0 = blk * BM;
  const int colbase = wave * CPW;

  if (tid < BM) {
    int r = row0 + tid;
    degmask[tid] = (r < M && off[r + 1] > off[r]) ? 1.f : 0.f;
  }

  f32x4 acc[4][NCF] = {};

#pragma unroll
  for (int kh = 0; kh < 2; ++kh) {
    __syncthreads();
    const unsigned short* base = (kh == 0) ? A1 : A2;
#pragma unroll
    for (int it = 0; it < 4; ++it) {
      int chunk = tid + it * 256;
      int row = chunk >> 4, c16 = chunk & 15;
      int gr = row0 + row; if (gr > M - 1) gr = M - 1;
      short8 v = *(const short8*)(base + (size_t)gr * 128 + c16 * 8);
      int byteoff = row * 256 + ((c16 * 16) ^ ((row & 7) << 4));
      *(short8*)((char*)As + byteoff) = v;
    }
#pragma unroll
    for (int it = 0; it < (N * 16) / 256; ++it) {
      int chunk = tid + it * 256;
      int n = chunk >> 4, c16 = chunk & 15;
      short8 v = *(const short8*)(WT + (size_t)n * 256 + kh * 128 + c16 * 8);
      int byteoff = n * 256 + ((c16 * 16) ^ ((n & 7) << 4));
      *(short8*)((char*)Ws + byteoff) = v;
    }
    __syncthreads();

#pragma unroll
    for (int ks = 0; ks < 4; ++ks) {
      short8 af[4];
#pragma unroll
      for (int rf = 0; rf < 4; ++rf) {
        int row = rf * 16 + (lane & 15);
        int c16 = ks * 4 + (lane >> 4);
        int byteoff = row * 256 + ((c16 * 16) ^ ((row & 7) << 4));
        af[rf] = *(const short8*)((const char*)As + byteoff);
      }
      short8 wf[NCF];
#pragma unroll
      for (int cf = 0; cf < NCF; ++cf) {
        int n = colbase + cf * 16 + (lane & 15);
        int c16 = ks * 4 + (lane >> 4);
        int byteoff = n * 256 + ((c16 * 16) ^ ((n & 7) << 4));
        wf[cf] = *(const short8*)((const char*)Ws + byteoff);
      }
#pragma unroll
      for (int rf = 0; rf < 4; ++rf)
#pragma unroll
        for (int cf = 0; cf < NCF; ++cf)
          acc[rf][cf] = __builtin_amdgcn_mfma_f32_16x16x32_bf16(
              af[rf], wf[cf], acc[rf][cf], 0, 0, 0);
    }
  }

  // C/D layout: col=lane&15, row=(lane>>4)*4+j  [m89 verified]
#pragma unroll
  for (int cf = 0; cf < NCF; ++cf) {
    int c = colbase + cf * 16 + (lane & 15);
    float bb0 = b0[c], bbe = be[c];
#pragma unroll
    for (int rf = 0; rf < 4; ++rf) {
#pragma unroll
      for (int j = 0; j < 4; ++j) {
        int lr = rf * 16 + (lane >> 4) * 4 + j;
        int r = row0 + lr;
        if (r < M) {
          float v = acc[rf][cf][j] + bb0 + degmask[lr] * bbe;
          if (LRELU) v = (v >= 0.f) ? v : 0.01f * v;
          if (OUTBF16)
            ((unsigned short*)outv)[(size_t)r * N + c] = f2bf(v);
          else
            ((float*)outv)[(size_t)r * N + c] = v;
        }
      }
    }
  }
}

extern "C" void kernel_launch(void* const* d_in, const int* in_sizes, int n_in,
                              void* d_out, int out_size, void* d_ws,
                              size_t ws_size, hipStream_t stream) {
  const float* emb_u = (const float*)d_in[0];
  const float* emb_i = (const float*)d_in[1];
  const float* W1_0  = (const float*)d_in[2];
  const float* b1_0  = (const float*)d_in[3];
  const float* W1_ui = (const float*)d_in[4];
  const float* b1_ui = (const float*)d_in[5];
  const float* W1_iu = (const float*)d_in[6];
  const float* b1_iu = (const float*)d_in[7];
  const float* W2_0  = (const float*)d_in[8];
  const float* b2_0  = (const float*)d_in[9];
  const float* W2_ui = (const float*)d_in[10];
  const float* b2_ui = (const float*)d_in[11];
  const float* W2_iu = (const float*)d_in[12];
  const float* b2_iu = (const float*)d_in[13];
  const int* src_ui = (const int*)d_in[14];
  const int* dst_ui = (const int*)d_in[15];
  const int* src_iu = (const int*)d_in[16];
  const int* dst_iu = (const int*)d_in[17];
  float* out = (float*)d_out;

  // ---- workspace layout (~107 MB) ----
  char* p = (char*)d_ws;
  unsigned short* WT1i = (unsigned short*)p; p += 65536;
  unsigned short* WT1u = (unsigned short*)p; p += 65536;
  unsigned short* WT2i = (unsigned short*)p; p += 32768;
  unsigned short* WT2u = (unsigned short*)p; p += 32768;
  int* off_ui = (int*)p; p += 400128;
  int* off_iu = (int*)p; p += 400128;
  int* csr_ui = (int*)p; p += 2000000;
  int* csr_iu = (int*)p; p += 2000000;
  int* tot_ui = (int*)p; p += 2048;
  int* tot_iu = (int*)p; p += 2048;
  const size_t FB = (size_t)N_USER * 128 * 2;  // 25.6 MB
  unsigned short* ebu  = (unsigned short*)p; p += FB;  // -> hu (in place)
  unsigned short* ebi  = (unsigned short*)p; p += FB;  // -> hi (in place)
  unsigned short* aggA = (unsigned short*)p; p += FB;
  unsigned short* aggB = (unsigned short*)p; p += FB;
  // cursors alias aggA/aggB region (dead once L1 agg writes)
  int* cnt_i = (int*)aggA;            // counts, then off built from them
  int* cnt_u = cnt_i + N_USER;
  int* cur_i = cnt_u + N_USER;        // fill cursors
  int* cur_u = cur_i + N_USER;
  unsigned short* hu = ebu;
  unsigned short* hi = ebi;

  const int EB = (NEDGE + 255) / 256;   // 1954
  const int NB = (N_USER + 255) / 256;  // 391
  const int GG = (N_USER + 63) / 64;    // 1563

  hipMemsetAsync(cnt_i, 0, 4 * N_USER * sizeof(int), stream);
  setup_k<<<16792, 256, 0, stream>>>(W1_0, W1_ui, W1_iu, W2_0, W2_ui, W2_iu,
                                     WT1i, WT1u, WT2i, WT2u, emb_u, emb_i,
                                     ebu, ebi, dst_ui, cnt_i, dst_iu, cnt_u);
  scan1m_k<<<2 * NB, 256, 0, stream>>>(cnt_i, off_ui, tot_ui, cnt_u, off_iu,
                                       tot_iu, N_USER, NB);
  scan2m_k<<<2, 512, 0, stream>>>(tot_ui, tot_iu, NB);
  scan3m_k<<<2 * NB, 256, 0, stream>>>(off_ui, tot_ui, off_iu, tot_iu, N_USER,
                                       NEDGE, NB);
  fill2_k<<<2 * EB, 256, 0, stream>>>(src_ui, dst_ui, off_ui, cur_i, csr_ui,
                                      src_iu, dst_iu, off_iu, cur_u, csr_iu,
                                      NEDGE, EB);

  // ---- layer 1: bf16 gather-mean (both dirs), fused GEMM+lrelu ----
  agg2_k<<<2 * 6250, 256, 0, stream>>>(
      ebu, off_ui, csr_ui, aggA, ebi, off_iu, csr_iu, aggB, 6250);
  gemm2_k<128, true, true><<<2 * GG, 256, 0, stream>>>(
      ebi, aggA, WT1i, b1_0, b1_ui, off_ui, hi,
      ebu, aggB, WT1u, b1_0, b1_iu, off_iu, hu, N_USER, GG);

  // ---- layer 2: bf16 gather-mean (both dirs), fused GEMM -> fp32 out ----
  agg2_k<<<2 * 6250, 256, 0, stream>>>(
      hu, off_ui, csr_ui, aggA, hi, off_iu, csr_iu, aggB, 6250);
  gemm2_k<64, false, false><<<2 * GG, 256, 0, stream>>>(
      hi, aggA, WT2i, b2_0, b2_ui, off_ui, out + (size_t)N_USER * 64,
      hu, aggB, WT2u, b2_0, b2_iu, off_iu, out, N_USER, GG);
}